// Round 1
// baseline (7502.489 us; speedup 1.0000x reference)
//
#include <hip/hip_runtime.h>
#include <cstdint>
#include <cstddef>

typedef short s16x8 __attribute__((ext_vector_type(8)));
typedef float f32x4 __attribute__((ext_vector_type(4)));

__device__ __forceinline__ f32x4 mfma16(s16x8 a, s16x8 b, f32x4 c) {
  return __builtin_amdgcn_mfma_f32_16x16x32_bf16(a, b, c, 0, 0, 0);
}

__device__ __forceinline__ unsigned short f2bf(float f) {
  unsigned u = __float_as_uint(f);
  u = (u + 0x7FFFu + ((u >> 16) & 1u)) >> 16;
  return (unsigned short)u;
}

// ---------------- fp32 -> bf16 conversion ----------------
__global__ void f2bf_kernel(const float* __restrict__ src,
                            unsigned short* __restrict__ dst, int n) {
  int i = (blockIdx.x * blockDim.x + threadIdx.x) * 4;
  if (i >= n) return;
  float4 v = *(const float4*)(src + i);
  ushort4 o;
  o.x = f2bf(v.x); o.y = f2bf(v.y); o.z = f2bf(v.z); o.w = f2bf(v.w);
  *(ushort4*)(dst + i) = o;
}

// ---------------- GEMM: C[M,N] = A[M,K] * W[N,K]^T + bias ----------------
// 128x128 tile, BK=32, 4 waves in 2x2, each wave 64x64 (4x4 of 16x16 tiles).
__global__ __launch_bounds__(256) void gemm_bias(
    const unsigned short* __restrict__ A,
    const unsigned short* __restrict__ W,
    const float* __restrict__ bias,
    float* __restrict__ C,
    int M, int N, int K)
{
  __shared__ unsigned short As[128 * 40];
  __shared__ unsigned short Bs[128 * 40];
  const int bm = blockIdx.x, bn = blockIdx.y;
  const int tid = threadIdx.x;
  const int lane = tid & 63, wave = tid >> 6;
  const int wm = wave & 1, wn = wave >> 1;
  const int lr = lane & 15, quad = lane >> 4;
  f32x4 acc[4][4] = {};
  const size_t abase = (size_t)bm * 128 * K;
  const size_t bbase = (size_t)bn * 128 * K;
  for (int k0 = 0; k0 < K; k0 += 32) {
#pragma unroll
    for (int u0 = 0; u0 < 2; u0++) {
      int u = tid + u0 * 256;
      int row = u >> 2, seg = u & 3;
      *(uint4*)(As + row * 40 + seg * 8) =
          *(const uint4*)(A + abase + (size_t)row * K + k0 + seg * 8);
      *(uint4*)(Bs + row * 40 + seg * 8) =
          *(const uint4*)(W + bbase + (size_t)row * K + k0 + seg * 8);
    }
    __syncthreads();
    s16x8 af[4], bf[4];
#pragma unroll
    for (int i = 0; i < 4; i++)
      af[i] = *(const s16x8*)(As + (wm * 64 + i * 16 + lr) * 40 + quad * 8);
#pragma unroll
    for (int j = 0; j < 4; j++)
      bf[j] = *(const s16x8*)(Bs + (wn * 64 + j * 16 + lr) * 40 + quad * 8);
#pragma unroll
    for (int i = 0; i < 4; i++)
#pragma unroll
      for (int j = 0; j < 4; j++)
        acc[i][j] = mfma16(af[i], bf[j], acc[i][j]);
    __syncthreads();
  }
#pragma unroll
  for (int i = 0; i < 4; i++)
#pragma unroll
    for (int j = 0; j < 4; j++) {
      int col = bn * 128 + wn * 64 + j * 16 + lr;
      float bv = bias ? bias[col] : 0.0f;
#pragma unroll
      for (int r = 0; r < 4; r++) {
        int row = bm * 128 + wm * 64 + i * 16 + quad * 4 + r;
        C[(size_t)row * N + col] = acc[i][j][r] + bv;
      }
    }
}

// ---------------- persistent LSTM recurrence ----------------
#define REC_BLOCKS 64

__device__ __forceinline__ void grid_sync(unsigned* cnt, unsigned target) {
  __syncthreads();
  if (threadIdx.x == 0) {
    __threadfence();  // release: h/y writes visible device-wide (cross-XCD)
    __hip_atomic_fetch_add(cnt, 1u, __ATOMIC_RELEASE, __HIP_MEMORY_SCOPE_AGENT);
    while (__hip_atomic_load(cnt, __ATOMIC_ACQUIRE, __HIP_MEMORY_SCOPE_AGENT) < target)
      __builtin_amdgcn_s_sleep(1);
    __threadfence();  // acquire: invalidate stale cached h lines
  }
  __syncthreads();
}

// 64 blocks x 512 threads. Block owns 16 h-dims (64 Whh rows, all 4 gates).
// 8 waves = (kq in 0..1: K-half) x (nq in 0..3: gate). Whh slice lives in
// registers as persistent MFMA B-fragments (64 VGPRs/lane).
__global__ __launch_bounds__(512) void lstm_rec(
    const float* __restrict__ ih,            // [(b*T+t)*4096 + g*1024 + d]
    const unsigned short* __restrict__ Whh,  // [4096,1024] bf16
    unsigned short* __restrict__ hbuf,       // [2][32][1024] bf16 double buffer
    unsigned short* __restrict__ ybf,        // [(b*T+t)*1024 + d] or null
    float* __restrict__ yf,                  // same, fp32, or null
    unsigned* __restrict__ cnt)
{
  const int T = 256, H = 1024, B = 32;
  const int blk = blockIdx.x;
  const int tid = threadIdx.x;
  const int lane = tid & 63, wave = tid >> 6;
  const int nq = wave & 3;   // gate index
  const int kq = wave >> 2;  // K half (512 each)
  const int lr = lane & 15, quad = lane >> 4;

  __shared__ float red[2][32][68];
  __shared__ float pre[32][68];

  // persistent weight B-fragments: row = nq*1024 + blk*16 + lr
  s16x8 bfrag[16];
  {
    const unsigned short* wp =
        Whh + (size_t)(nq * 1024 + blk * 16 + lr) * 1024 + kq * 512 + quad * 8;
#pragma unroll
    for (int kb = 0; kb < 16; kb++) bfrag[kb] = *(const s16x8*)(wp + kb * 32);
  }

  const int batch = tid >> 4, jj = tid & 15;  // each thread owns (batch, dim)
  hbuf[batch * H + blk * 16 + jj] = 0;        // h0 = 0 in buffer 0
  float cst = 0.0f;                           // c state lives in this register

  unsigned phase = 1;
  grid_sync(cnt, REC_BLOCKS * phase); phase++;

  for (int t = 0; t < T; t++) {
    const unsigned short* hcur = hbuf + (t & 1) * (B * H);
    unsigned short* hnxt = hbuf + ((t + 1) & 1) * (B * H);

    // pre_partial[batch 0..31][16 cols of gate nq] over K-half kq
    f32x4 acc0 = {0.f, 0.f, 0.f, 0.f}, acc1 = {0.f, 0.f, 0.f, 0.f};
    const unsigned short* hp = hcur + kq * 512 + quad * 8;
#pragma unroll
    for (int kb = 0; kb < 16; kb++) {
      s16x8 a0 = *(const s16x8*)(hp + lr * H + kb * 32);
      s16x8 a1 = *(const s16x8*)(hp + (16 + lr) * H + kb * 32);
      acc0 = mfma16(a0, bfrag[kb], acc0);
      acc1 = mfma16(a1, bfrag[kb], acc1);
    }
#pragma unroll
    for (int r = 0; r < 4; r++) {
      red[kq][quad * 4 + r][nq * 16 + lr] = acc0[r];
      red[kq][16 + quad * 4 + r][nq * 16 + lr] = acc1[r];
    }
    __syncthreads();

    // reduce K-halves + add precomputed ih (bias already folded in)
    {
      int o = tid * 4;
      int b2 = o >> 6, col0 = o & 63;
      int g = col0 >> 4, j0 = col0 & 15;
      const float* ihp =
          ih + ((size_t)(b2 * T + t)) * 4096 + g * 1024 + blk * 16 + j0;
      float4 iv = *(const float4*)ihp;
      float4 r0 = *(const float4*)&red[0][b2][col0];
      float4 r1 = *(const float4*)&red[1][b2][col0];
      float4 pv = { r0.x + r1.x + iv.x, r0.y + r1.y + iv.y,
                    r0.z + r1.z + iv.z, r0.w + r1.w + iv.w };
      *(float4*)&pre[b2][col0] = pv;
    }
    __syncthreads();

    // gates + state update: thread owns (batch, jj)
    {
      float pi = pre[batch][jj];
      float pf = pre[batch][16 + jj];
      float pg = pre[batch][32 + jj];
      float po = pre[batch][48 + jj];
      float ig = 1.0f / (1.0f + __expf(-pi));
      float fg = 1.0f / (1.0f + __expf(-pf));
      float gg = 1.0f - 2.0f / (__expf(2.0f * pg) + 1.0f);  // tanh, overflow-safe
      float og = 1.0f / (1.0f + __expf(-po));
      cst = fg * cst + ig * gg;
      float hv = og * (1.0f - 2.0f / (__expf(2.0f * cst) + 1.0f));
      unsigned short hb = f2bf(hv);
      hnxt[batch * H + blk * 16 + jj] = hb;
      size_t yi = ((size_t)(batch * T + t)) * H + blk * 16 + jj;
      if (ybf) ybf[yi] = hb;
      if (yf) yf[yi] = hv;
    }
    grid_sync(cnt, REC_BLOCKS * phase); phase++;
  }
}

// ---------------- launcher ----------------
extern "C" void kernel_launch(void* const* d_in, const int* in_sizes, int n_in,
                              void* d_out, int out_size, void* d_ws, size_t ws_size,
                              hipStream_t stream) {
  const float* x    = (const float*)d_in[0];
  const float* Wih0 = (const float*)d_in[1];
  const float* Whh0 = (const float*)d_in[2];
  const float* b0   = (const float*)d_in[3];
  const float* Wih1 = (const float*)d_in[4];
  const float* Whh1 = (const float*)d_in[5];
  const float* b1   = (const float*)d_in[6];
  float* out = (float*)d_out;

  const size_t NW = 4096ull * 1024;  // weight elems
  const size_t NX = 8192ull * 1024;  // x / y elems (B*T x H)

  char* ws = (char*)d_ws;
  size_t off = 0;
  auto alloc = [&](size_t bytes) {
    char* p = ws + off;
    off += (bytes + 255) & ~(size_t)255;
    return p;
  };
  unsigned short* wih0b = (unsigned short*)alloc(NW * 2);
  unsigned short* whh0b = (unsigned short*)alloc(NW * 2);
  unsigned short* wih1b = (unsigned short*)alloc(NW * 2);
  unsigned short* whh1b = (unsigned short*)alloc(NW * 2);
  unsigned short* xb    = (unsigned short*)alloc(NX * 2);
  unsigned short* y1b   = (unsigned short*)alloc(NX * 2);
  float* ihbuf          = (float*)alloc(8192ull * 4096 * 4);
  unsigned short* hbuf  = (unsigned short*)alloc(2ull * 32 * 1024 * 2);
  unsigned* cnt         = (unsigned*)alloc(256);

  hipMemsetAsync(cnt, 0, 8, stream);

  f2bf_kernel<<<NW / 1024, 256, 0, stream>>>(Wih0, wih0b, (int)NW);
  f2bf_kernel<<<NW / 1024, 256, 0, stream>>>(Whh0, whh0b, (int)NW);
  f2bf_kernel<<<NW / 1024, 256, 0, stream>>>(Wih1, wih1b, (int)NW);
  f2bf_kernel<<<NW / 1024, 256, 0, stream>>>(Whh1, whh1b, (int)NW);
  f2bf_kernel<<<NX / 1024, 256, 0, stream>>>(x, xb, (int)NX);

  // layer 1
  gemm_bias<<<dim3(64, 32), 256, 0, stream>>>(xb, wih0b, b0, ihbuf, 8192, 4096, 1024);
  lstm_rec<<<REC_BLOCKS, 512, 0, stream>>>(ihbuf, whh0b, hbuf, y1b,
                                           (float*)nullptr, cnt);
  // layer 2
  gemm_bias<<<dim3(64, 32), 256, 0, stream>>>(y1b, wih1b, b1, ihbuf, 8192, 4096, 1024);
  lstm_rec<<<REC_BLOCKS, 512, 0, stream>>>(ihbuf, whh1b, hbuf,
                                           (unsigned short*)nullptr, out, cnt + 1);
}

// Round 2
// 6288.074 us; speedup vs baseline: 1.1931x; 1.1931x over previous
//
#include <hip/hip_runtime.h>
#include <cstdint>
#include <cstddef>

typedef short s16x8 __attribute__((ext_vector_type(8)));
typedef float f32x4 __attribute__((ext_vector_type(4)));

__device__ __forceinline__ f32x4 mfma16(s16x8 a, s16x8 b, f32x4 c) {
  return __builtin_amdgcn_mfma_f32_16x16x32_bf16(a, b, c, 0, 0, 0);
}

__device__ __forceinline__ unsigned short f2bf(float f) {
  unsigned u = __float_as_uint(f);
  u = (u + 0x7FFFu + ((u >> 16) & 1u)) >> 16;
  return (unsigned short)u;
}

// ---------------- fp32 -> bf16 conversion ----------------
__global__ void f2bf_kernel(const float* __restrict__ src,
                            unsigned short* __restrict__ dst, int n) {
  int i = (blockIdx.x * blockDim.x + threadIdx.x) * 4;
  if (i >= n) return;
  float4 v = *(const float4*)(src + i);
  ushort4 o;
  o.x = f2bf(v.x); o.y = f2bf(v.y); o.z = f2bf(v.z); o.w = f2bf(v.w);
  *(ushort4*)(dst + i) = o;
}

// ---------------- GEMM: C[M,N] = A[M,K] * W[N,K]^T + bias ----------------
__global__ __launch_bounds__(256) void gemm_bias(
    const unsigned short* __restrict__ A,
    const unsigned short* __restrict__ W,
    const float* __restrict__ bias,
    float* __restrict__ C,
    int M, int N, int K)
{
  __shared__ unsigned short As[128 * 40];
  __shared__ unsigned short Bs[128 * 40];
  const int bm = blockIdx.x, bn = blockIdx.y;
  const int tid = threadIdx.x;
  const int lane = tid & 63, wave = tid >> 6;
  const int wm = wave & 1, wn = wave >> 1;
  const int lr = lane & 15, quad = lane >> 4;
  f32x4 acc[4][4] = {};
  const size_t abase = (size_t)bm * 128 * K;
  const size_t bbase = (size_t)bn * 128 * K;
  for (int k0 = 0; k0 < K; k0 += 32) {
#pragma unroll
    for (int u0 = 0; u0 < 2; u0++) {
      int u = tid + u0 * 256;
      int row = u >> 2, seg = u & 3;
      *(uint4*)(As + row * 40 + seg * 8) =
          *(const uint4*)(A + abase + (size_t)row * K + k0 + seg * 8);
      *(uint4*)(Bs + row * 40 + seg * 8) =
          *(const uint4*)(W + bbase + (size_t)row * K + k0 + seg * 8);
    }
    __syncthreads();
    s16x8 af[4], bf[4];
#pragma unroll
    for (int i = 0; i < 4; i++)
      af[i] = *(const s16x8*)(As + (wm * 64 + i * 16 + lr) * 40 + quad * 8);
#pragma unroll
    for (int j = 0; j < 4; j++)
      bf[j] = *(const s16x8*)(Bs + (wn * 64 + j * 16 + lr) * 40 + quad * 8);
#pragma unroll
    for (int i = 0; i < 4; i++)
#pragma unroll
      for (int j = 0; j < 4; j++)
        acc[i][j] = mfma16(af[i], bf[j], acc[i][j]);
    __syncthreads();
  }
#pragma unroll
  for (int i = 0; i < 4; i++)
#pragma unroll
    for (int j = 0; j < 4; j++) {
      int col = bn * 128 + wn * 64 + j * 16 + lr;
      float bv = bias ? bias[col] : 0.0f;
#pragma unroll
      for (int r = 0; r < 4; r++) {
        int row = bm * 128 + wm * 64 + i * 16 + quad * 4 + r;
        C[(size_t)row * N + col] = acc[i][j][r] + bv;
      }
    }
}

// ---------------- persistent LSTM recurrence ----------------
#define REC_BLOCKS 64

// Barrier redesign (R1): the R0 version polled with ACQUIRE at agent scope,
// emitting buffer_inv (full L2 invalidate) EVERY poll iteration from all 64
// blocks, plus two buffer_wbl2 per step (__threadfence + release RMW).
// Now: one release RMW (one wbl2), RELAXED poll, ONE acquire fence after.
__device__ __forceinline__ void grid_sync(unsigned* cnt, unsigned target) {
  __syncthreads();  // compiler emits s_waitcnt vmcnt(0) before s_barrier:
                    // all h/y stores are in L2 before the release below
  if (threadIdx.x == 0) {
    __hip_atomic_fetch_add(cnt, 1u, __ATOMIC_RELEASE, __HIP_MEMORY_SCOPE_AGENT);
    while (__hip_atomic_load(cnt, __ATOMIC_RELAXED, __HIP_MEMORY_SCOPE_AGENT) < target)
      __builtin_amdgcn_s_sleep(2);
    __builtin_amdgcn_fence(__ATOMIC_ACQUIRE, "agent");  // single L1/L2 inv
  }
  __syncthreads();
}

// 64 blocks x 512 threads. Block owns 16 h-dims (64 Whh rows, all 4 gates).
// 8 waves = (kq in 0..1: K-half) x (nq in 0..3: gate). Whh slice lives in
// registers as persistent MFMA B-fragments (64 VGPRs/lane).
__global__ __launch_bounds__(512) void lstm_rec(
    const float* __restrict__ ih,            // [(b*T+t)*4096 + g*1024 + d]
    const unsigned short* __restrict__ Whh,  // [4096,1024] bf16
    unsigned short* __restrict__ hbuf,       // [2][32][1024] bf16 double buffer
    unsigned short* __restrict__ ybf,        // [(b*T+t)*1024 + d] or null
    float* __restrict__ yf,                  // same, fp32, or null
    unsigned* __restrict__ cnt)
{
  const int T = 256, H = 1024, B = 32;
  const int blk = blockIdx.x;
  const int tid = threadIdx.x;
  const int lane = tid & 63, wave = tid >> 6;
  const int nq = wave & 3;   // gate index
  const int kq = wave >> 2;  // K half (512 each)
  const int lr = lane & 15, quad = lane >> 4;

  __shared__ float red[2][32][68];
  __shared__ float pre[32][68];

  // persistent weight B-fragments: row = nq*1024 + blk*16 + lr
  s16x8 bfrag[16];
  {
    const unsigned short* wp =
        Whh + (size_t)(nq * 1024 + blk * 16 + lr) * 1024 + kq * 512 + quad * 8;
#pragma unroll
    for (int kb = 0; kb < 16; kb++) bfrag[kb] = *(const s16x8*)(wp + kb * 32);
  }

  const int batch = tid >> 4, jj = tid & 15;  // each thread owns (batch, dim)
  hbuf[batch * H + blk * 16 + jj] = 0;        // h0 = 0 in buffer 0
  float cst = 0.0f;                           // c state lives in this register

  // reduce-phase thread mapping (tid -> (b2, col0) in the 32x64 pre-act tile)
  const int o = tid * 4;
  const int b2 = o >> 6, col0 = o & 63;
  const int gg_ = col0 >> 4, j0 = col0 & 15;
  const float* ihp0 = ih + (size_t)b2 * T * 4096 + gg_ * 1024 + blk * 16 + j0;

  // prefetch ih for t=0 BEFORE the first barrier (t-dependent only)
  float4 iv = *(const float4*)(ihp0);

  unsigned phase = 1;
  grid_sync(cnt, REC_BLOCKS * phase); phase++;

  for (int t = 0; t < T; t++) {
    const unsigned short* hcur = hbuf + (t & 1) * (B * H);
    unsigned short* hnxt = hbuf + ((t + 1) & 1) * (B * H);

    // pre_partial[batch 0..31][16 cols of gate nq] over K-half kq
    f32x4 acc0 = {0.f, 0.f, 0.f, 0.f}, acc1 = {0.f, 0.f, 0.f, 0.f};
    const unsigned short* hp = hcur + kq * 512 + quad * 8;
#pragma unroll
    for (int kb = 0; kb < 16; kb++) {
      s16x8 a0 = *(const s16x8*)(hp + lr * H + kb * 32);
      s16x8 a1 = *(const s16x8*)(hp + (16 + lr) * H + kb * 32);
      acc0 = mfma16(a0, bfrag[kb], acc0);
      acc1 = mfma16(a1, bfrag[kb], acc1);
    }
#pragma unroll
    for (int r = 0; r < 4; r++) {
      red[kq][quad * 4 + r][nq * 16 + lr] = acc0[r];
      red[kq][16 + quad * 4 + r][nq * 16 + lr] = acc1[r];
    }
    __syncthreads();

    // reduce K-halves + add prefetched ih (bias already folded in)
    {
      float4 r0 = *(const float4*)&red[0][b2][col0];
      float4 r1 = *(const float4*)&red[1][b2][col0];
      float4 pv = { r0.x + r1.x + iv.x, r0.y + r1.y + iv.y,
                    r0.z + r1.z + iv.z, r0.w + r1.w + iv.w };
      *(float4*)&pre[b2][col0] = pv;
    }
    __syncthreads();

    // gates + state update: thread owns (batch, jj)
    {
      float pi = pre[batch][jj];
      float pf = pre[batch][16 + jj];
      float pg = pre[batch][32 + jj];
      float po = pre[batch][48 + jj];
      float ig = 1.0f / (1.0f + __expf(-pi));
      float fg = 1.0f / (1.0f + __expf(-pf));
      float g  = 1.0f - 2.0f / (__expf(2.0f * pg) + 1.0f);  // tanh, overflow-safe
      float og = 1.0f / (1.0f + __expf(-po));
      cst = fg * cst + ig * g;
      float hv = og * (1.0f - 2.0f / (__expf(2.0f * cst) + 1.0f));
      unsigned short hb = f2bf(hv);
      hnxt[batch * H + blk * 16 + jj] = hb;
      size_t yi = ((size_t)(batch * T + t)) * H + blk * 16 + jj;
      if (ybf) ybf[yi] = hb;
      if (yf) yf[yi] = hv;
    }

    // prefetch next step's ih before the barrier (hides post-inv LLC miss)
    if (t + 1 < T) iv = *(const float4*)(ihp0 + (size_t)(t + 1) * 4096);

    grid_sync(cnt, REC_BLOCKS * phase); phase++;
  }
}

// ---------------- launcher ----------------
extern "C" void kernel_launch(void* const* d_in, const int* in_sizes, int n_in,
                              void* d_out, int out_size, void* d_ws, size_t ws_size,
                              hipStream_t stream) {
  const float* x    = (const float*)d_in[0];
  const float* Wih0 = (const float*)d_in[1];
  const float* Whh0 = (const float*)d_in[2];
  const float* b0   = (const float*)d_in[3];
  const float* Wih1 = (const float*)d_in[4];
  const float* Whh1 = (const float*)d_in[5];
  const float* b1   = (const float*)d_in[6];
  float* out = (float*)d_out;

  const size_t NW = 4096ull * 1024;  // weight elems
  const size_t NX = 8192ull * 1024;  // x / y elems (B*T x H)

  char* ws = (char*)d_ws;
  size_t off = 0;
  auto alloc = [&](size_t bytes) {
    char* p = ws + off;
    off += (bytes + 255) & ~(size_t)255;
    return p;
  };
  unsigned short* wih0b = (unsigned short*)alloc(NW * 2);
  unsigned short* whh0b = (unsigned short*)alloc(NW * 2);
  unsigned short* wih1b = (unsigned short*)alloc(NW * 2);
  unsigned short* whh1b = (unsigned short*)alloc(NW * 2);
  unsigned short* xb    = (unsigned short*)alloc(NX * 2);
  unsigned short* y1b   = (unsigned short*)alloc(NX * 2);
  float* ihbuf          = (float*)alloc(8192ull * 4096 * 4);
  unsigned short* hbuf  = (unsigned short*)alloc(2ull * 32 * 1024 * 2);
  unsigned* cnt         = (unsigned*)alloc(256);

  hipMemsetAsync(cnt, 0, 8, stream);

  f2bf_kernel<<<NW / 1024, 256, 0, stream>>>(Wih0, wih0b, (int)NW);
  f2bf_kernel<<<NW / 1024, 256, 0, stream>>>(Whh0, whh0b, (int)NW);
  f2bf_kernel<<<NW / 1024, 256, 0, stream>>>(Wih1, wih1b, (int)NW);
  f2bf_kernel<<<NW / 1024, 256, 0, stream>>>(Whh1, whh1b, (int)NW);
  f2bf_kernel<<<NX / 1024, 256, 0, stream>>>(x, xb, (int)NX);

  // layer 1
  gemm_bias<<<dim3(64, 32), 256, 0, stream>>>(xb, wih0b, b0, ihbuf, 8192, 4096, 1024);
  lstm_rec<<<REC_BLOCKS, 512, 0, stream>>>(ihbuf, whh0b, hbuf, y1b,
                                           (float*)nullptr, cnt);
  // layer 2
  gemm_bias<<<dim3(64, 32), 256, 0, stream>>>(y1b, wih1b, b1, ihbuf, 8192, 4096, 1024);
  lstm_rec<<<REC_BLOCKS, 512, 0, stream>>>(ihbuf, whh1b, hbuf,
                                           (unsigned short*)nullptr, out, cnt + 1);
}

// Round 3
// 5952.131 us; speedup vs baseline: 1.2605x; 1.0564x over previous
//
#include <hip/hip_runtime.h>
#include <cstdint>
#include <cstddef>

typedef short s16x8 __attribute__((ext_vector_type(8)));
typedef float f32x4 __attribute__((ext_vector_type(4)));

__device__ __forceinline__ f32x4 mfma16(s16x8 a, s16x8 b, f32x4 c) {
  return __builtin_amdgcn_mfma_f32_16x16x32_bf16(a, b, c, 0, 0, 0);
}

__device__ __forceinline__ unsigned short f2bf(float f) {
  unsigned u = __float_as_uint(f);
  u = (u + 0x7FFFu + ((u >> 16) & 1u)) >> 16;
  return (unsigned short)u;
}

// ---------------- fp32 -> bf16 conversion ----------------
__global__ void f2bf_kernel(const float* __restrict__ src,
                            unsigned short* __restrict__ dst, int n) {
  int i = (blockIdx.x * blockDim.x + threadIdx.x) * 4;
  if (i >= n) return;
  float4 v = *(const float4*)(src + i);
  ushort4 o;
  o.x = f2bf(v.x); o.y = f2bf(v.y); o.z = f2bf(v.z); o.w = f2bf(v.w);
  *(ushort4*)(dst + i) = o;
}

// ---------------- GEMM: C[M,N] = A[M,K] * W[N,K]^T + bias ----------------
__global__ __launch_bounds__(256) void gemm_bias(
    const unsigned short* __restrict__ A,
    const unsigned short* __restrict__ W,
    const float* __restrict__ bias,
    float* __restrict__ C,
    int M, int N, int K)
{
  __shared__ unsigned short As[128 * 40];
  __shared__ unsigned short Bs[128 * 40];
  const int bm = blockIdx.x, bn = blockIdx.y;
  const int tid = threadIdx.x;
  const int lane = tid & 63, wave = tid >> 6;
  const int wm = wave & 1, wn = wave >> 1;
  const int lr = lane & 15, quad = lane >> 4;
  f32x4 acc[4][4] = {};
  const size_t abase = (size_t)bm * 128 * K;
  const size_t bbase = (size_t)bn * 128 * K;
  for (int k0 = 0; k0 < K; k0 += 32) {
#pragma unroll
    for (int u0 = 0; u0 < 2; u0++) {
      int u = tid + u0 * 256;
      int row = u >> 2, seg = u & 3;
      *(uint4*)(As + row * 40 + seg * 8) =
          *(const uint4*)(A + abase + (size_t)row * K + k0 + seg * 8);
      *(uint4*)(Bs + row * 40 + seg * 8) =
          *(const uint4*)(W + bbase + (size_t)row * K + k0 + seg * 8);
    }
    __syncthreads();
    s16x8 af[4], bf[4];
#pragma unroll
    for (int i = 0; i < 4; i++)
      af[i] = *(const s16x8*)(As + (wm * 64 + i * 16 + lr) * 40 + quad * 8);
#pragma unroll
    for (int j = 0; j < 4; j++)
      bf[j] = *(const s16x8*)(Bs + (wn * 64 + j * 16 + lr) * 40 + quad * 8);
#pragma unroll
    for (int i = 0; i < 4; i++)
#pragma unroll
      for (int j = 0; j < 4; j++)
        acc[i][j] = mfma16(af[i], bf[j], acc[i][j]);
    __syncthreads();
  }
#pragma unroll
  for (int i = 0; i < 4; i++)
#pragma unroll
    for (int j = 0; j < 4; j++) {
      int col = bn * 128 + wn * 64 + j * 16 + lr;
      float bv = bias ? bias[col] : 0.0f;
#pragma unroll
      for (int r = 0; r < 4; r++) {
        int row = bm * 128 + wm * 64 + i * 16 + quad * 4 + r;
        C[(size_t)row * N + col] = acc[i][j][r] + bv;
      }
    }
}

// ---------------- persistent LSTM recurrence ----------------
#define REC_BLOCKS 64
#define FLAG_STRIDE 32  // uints -> 128 B per flag, one cacheline each

// Flag-tree barrier (R2). R1's version funneled 64 release fetch_adds into
// ONE cacheline per step: exclusive-ownership migration across 8 XCDs
// serializes at ~180ns each = ~11.5us/step (matches measured). Now: each
// block release-stores its OWN 128B-spaced flag (64 parallel stores, no
// ownership contention); wave 0's 64 lanes each poll a different flag
// (parallel relaxed agent loads); one acquire fence after convergence.
__device__ __forceinline__ void grid_sync(unsigned* flags, unsigned phase, int blk) {
  __syncthreads();  // compiler drains vmcnt: h/y stores are in L2 first
  if (threadIdx.x < 64) {
    if (threadIdx.x == 0)
      __hip_atomic_store(flags + (size_t)blk * FLAG_STRIDE, phase,
                         __ATOMIC_RELEASE, __HIP_MEMORY_SCOPE_AGENT);
    const unsigned* f = flags + (size_t)threadIdx.x * FLAG_STRIDE;
    while (__hip_atomic_load(f, __ATOMIC_RELAXED, __HIP_MEMORY_SCOPE_AGENT) < phase)
      __builtin_amdgcn_s_sleep(1);
    __builtin_amdgcn_fence(__ATOMIC_ACQUIRE, "agent");  // one L1/L2 inv
  }
  __syncthreads();
}

// 64 blocks x 512 threads. Block owns 16 h-dims (64 Whh rows, all 4 gates).
// 8 waves = (kq in 0..1: K-half) x (nq in 0..3: gate). Whh slice lives in
// registers as persistent MFMA B-fragments (64 VGPRs/lane).
__global__ __launch_bounds__(512) void lstm_rec(
    const float* __restrict__ ih,            // [(b*T+t)*4096 + g*1024 + d]
    const unsigned short* __restrict__ Whh,  // [4096,1024] bf16
    unsigned short* __restrict__ hbuf,       // [2][32][1024] bf16 double buffer
    unsigned short* __restrict__ ybf,        // [(b*T+t)*1024 + d] or null
    float* __restrict__ yf,                  // same, fp32, or null
    unsigned* __restrict__ flags)
{
  const int T = 256, H = 1024, B = 32;
  const int blk = blockIdx.x;
  const int tid = threadIdx.x;
  const int lane = tid & 63, wave = tid >> 6;
  const int nq = wave & 3;   // gate index
  const int kq = wave >> 2;  // K half (512 each)
  const int lr = lane & 15, quad = lane >> 4;

  __shared__ float red[2][32][68];
  __shared__ float pre[32][68];

  // persistent weight B-fragments: row = nq*1024 + blk*16 + lr
  s16x8 bfrag[16];
  {
    const unsigned short* wp =
        Whh + (size_t)(nq * 1024 + blk * 16 + lr) * 1024 + kq * 512 + quad * 8;
#pragma unroll
    for (int kb = 0; kb < 16; kb++) bfrag[kb] = *(const s16x8*)(wp + kb * 32);
  }

  const int batch = tid >> 4, jj = tid & 15;  // each thread owns (batch, dim)
  hbuf[batch * H + blk * 16 + jj] = 0;        // h0 = 0 in buffer 0
  float cst = 0.0f;                           // c state lives in this register

  // reduce-phase thread mapping (tid -> (b2, col0) in the 32x64 pre-act tile)
  const int o = tid * 4;
  const int b2 = o >> 6, col0 = o & 63;
  const int gg_ = col0 >> 4, j0 = col0 & 15;
  const float* ihp0 = ih + (size_t)b2 * T * 4096 + gg_ * 1024 + blk * 16 + j0;

  // prefetch ih for t=0 BEFORE the first barrier (t-dependent only)
  float4 iv = *(const float4*)(ihp0);

  unsigned phase = 1;
  grid_sync(flags, phase, blk); phase++;

  for (int t = 0; t < T; t++) {
    const unsigned short* hcur = hbuf + (t & 1) * (B * H);
    unsigned short* hnxt = hbuf + ((t + 1) & 1) * (B * H);

    // pre_partial[batch 0..31][16 cols of gate nq] over K-half kq
    f32x4 acc0 = {0.f, 0.f, 0.f, 0.f}, acc1 = {0.f, 0.f, 0.f, 0.f};
    const unsigned short* hp = hcur + kq * 512 + quad * 8;
#pragma unroll
    for (int kb = 0; kb < 16; kb++) {
      s16x8 a0 = *(const s16x8*)(hp + lr * H + kb * 32);
      s16x8 a1 = *(const s16x8*)(hp + (16 + lr) * H + kb * 32);
      acc0 = mfma16(a0, bfrag[kb], acc0);
      acc1 = mfma16(a1, bfrag[kb], acc1);
    }
#pragma unroll
    for (int r = 0; r < 4; r++) {
      red[kq][quad * 4 + r][nq * 16 + lr] = acc0[r];
      red[kq][16 + quad * 4 + r][nq * 16 + lr] = acc1[r];
    }
    __syncthreads();

    // reduce K-halves + add prefetched ih (bias already folded in)
    {
      float4 r0 = *(const float4*)&red[0][b2][col0];
      float4 r1 = *(const float4*)&red[1][b2][col0];
      float4 pv = { r0.x + r1.x + iv.x, r0.y + r1.y + iv.y,
                    r0.z + r1.z + iv.z, r0.w + r1.w + iv.w };
      *(float4*)&pre[b2][col0] = pv;
    }
    __syncthreads();

    // gates + state update: thread owns (batch, jj)
    {
      float pi = pre[batch][jj];
      float pf = pre[batch][16 + jj];
      float pg = pre[batch][32 + jj];
      float po = pre[batch][48 + jj];
      float ig = 1.0f / (1.0f + __expf(-pi));
      float fg = 1.0f / (1.0f + __expf(-pf));
      float g  = 1.0f - 2.0f / (__expf(2.0f * pg) + 1.0f);  // tanh, overflow-safe
      float og = 1.0f / (1.0f + __expf(-po));
      cst = fg * cst + ig * g;
      float hv = og * (1.0f - 2.0f / (__expf(2.0f * cst) + 1.0f));
      unsigned short hb = f2bf(hv);
      hnxt[batch * H + blk * 16 + jj] = hb;
      size_t yi = ((size_t)(batch * T + t)) * H + blk * 16 + jj;
      if (ybf) ybf[yi] = hb;
      if (yf) yf[yi] = hv;
    }

    // prefetch next step's ih before the barrier (hides post-inv LLC miss)
    if (t + 1 < T) iv = *(const float4*)(ihp0 + (size_t)(t + 1) * 4096);

    grid_sync(flags, phase, blk); phase++;
  }
}

// ---------------- launcher ----------------
extern "C" void kernel_launch(void* const* d_in, const int* in_sizes, int n_in,
                              void* d_out, int out_size, void* d_ws, size_t ws_size,
                              hipStream_t stream) {
  const float* x    = (const float*)d_in[0];
  const float* Wih0 = (const float*)d_in[1];
  const float* Whh0 = (const float*)d_in[2];
  const float* b0   = (const float*)d_in[3];
  const float* Wih1 = (const float*)d_in[4];
  const float* Whh1 = (const float*)d_in[5];
  const float* b1   = (const float*)d_in[6];
  float* out = (float*)d_out;

  const size_t NW = 4096ull * 1024;  // weight elems
  const size_t NX = 8192ull * 1024;  // x / y elems (B*T x H)

  char* ws = (char*)d_ws;
  size_t off = 0;
  auto alloc = [&](size_t bytes) {
    char* p = ws + off;
    off += (bytes + 255) & ~(size_t)255;
    return p;
  };
  unsigned short* wih0b = (unsigned short*)alloc(NW * 2);
  unsigned short* whh0b = (unsigned short*)alloc(NW * 2);
  unsigned short* wih1b = (unsigned short*)alloc(NW * 2);
  unsigned short* whh1b = (unsigned short*)alloc(NW * 2);
  unsigned short* xb    = (unsigned short*)alloc(NX * 2);
  unsigned short* y1b   = (unsigned short*)alloc(NX * 2);
  float* ihbuf          = (float*)alloc(8192ull * 4096 * 4);
  unsigned short* hbuf  = (unsigned short*)alloc(2ull * 32 * 1024 * 2);
  unsigned* flags0      = (unsigned*)alloc(REC_BLOCKS * FLAG_STRIDE * 4);
  unsigned* flags1      = (unsigned*)alloc(REC_BLOCKS * FLAG_STRIDE * 4);

  hipMemsetAsync(flags0, 0, REC_BLOCKS * FLAG_STRIDE * 4 * 2, stream);

  f2bf_kernel<<<NW / 1024, 256, 0, stream>>>(Wih0, wih0b, (int)NW);
  f2bf_kernel<<<NW / 1024, 256, 0, stream>>>(Whh0, whh0b, (int)NW);
  f2bf_kernel<<<NW / 1024, 256, 0, stream>>>(Wih1, wih1b, (int)NW);
  f2bf_kernel<<<NW / 1024, 256, 0, stream>>>(Whh1, whh1b, (int)NW);
  f2bf_kernel<<<NX / 1024, 256, 0, stream>>>(x, xb, (int)NX);

  // layer 1
  gemm_bias<<<dim3(64, 32), 256, 0, stream>>>(xb, wih0b, b0, ihbuf, 8192, 4096, 1024);
  lstm_rec<<<REC_BLOCKS, 512, 0, stream>>>(ihbuf, whh0b, hbuf, y1b,
                                           (float*)nullptr, flags0);
  // layer 2
  gemm_bias<<<dim3(64, 32), 256, 0, stream>>>(y1b, wih1b, b1, ihbuf, 8192, 4096, 1024);
  lstm_rec<<<REC_BLOCKS, 512, 0, stream>>>(ihbuf, whh1b, hbuf,
                                           (unsigned short*)nullptr, out, flags1);
}

// Round 4
// 3451.129 us; speedup vs baseline: 2.1739x; 1.7247x over previous
//
#include <hip/hip_runtime.h>
#include <cstdint>
#include <cstddef>

typedef short s16x8 __attribute__((ext_vector_type(8)));
typedef float f32x4 __attribute__((ext_vector_type(4)));

__device__ __forceinline__ f32x4 mfma16(s16x8 a, s16x8 b, f32x4 c) {
  return __builtin_amdgcn_mfma_f32_16x16x32_bf16(a, b, c, 0, 0, 0);
}

__device__ __forceinline__ unsigned short f2bf(float f) {
  unsigned u = __float_as_uint(f);
  u = (u + 0x7FFFu + ((u >> 16) & 1u)) >> 16;
  return (unsigned short)u;
}

// LLC-coherent 16B load as 2x8B relaxed agent atomics (sc1: bypass L2, read
// the coherence point directly -> no acquire fence / buffer_inv needed).
__device__ __forceinline__ s16x8 load16_llc(const unsigned short* p) {
  union { unsigned long long u[2]; s16x8 v; } r;
  const unsigned long long* q = (const unsigned long long*)p;
  r.u[0] = __hip_atomic_load(q,     __ATOMIC_RELAXED, __HIP_MEMORY_SCOPE_AGENT);
  r.u[1] = __hip_atomic_load(q + 1, __ATOMIC_RELAXED, __HIP_MEMORY_SCOPE_AGENT);
  return r.v;
}

// ---------------- fp32 -> bf16 conversion ----------------
__global__ void f2bf_kernel(const float* __restrict__ src,
                            unsigned short* __restrict__ dst, int n) {
  int i = (blockIdx.x * blockDim.x + threadIdx.x) * 4;
  if (i >= n) return;
  float4 v = *(const float4*)(src + i);
  ushort4 o;
  o.x = f2bf(v.x); o.y = f2bf(v.y); o.z = f2bf(v.z); o.w = f2bf(v.w);
  *(ushort4*)(dst + i) = o;
}

// ---------------- GEMM: C[M,N] = A[M,K] * W[N,K]^T + bias ----------------
__global__ __launch_bounds__(256) void gemm_bias(
    const unsigned short* __restrict__ A,
    const unsigned short* __restrict__ W,
    const float* __restrict__ bias,
    float* __restrict__ C,
    int M, int N, int K)
{
  __shared__ unsigned short As[128 * 40];
  __shared__ unsigned short Bs[128 * 40];
  const int bm = blockIdx.x, bn = blockIdx.y;
  const int tid = threadIdx.x;
  const int lane = tid & 63, wave = tid >> 6;
  const int wm = wave & 1, wn = wave >> 1;
  const int lr = lane & 15, quad = lane >> 4;
  f32x4 acc[4][4] = {};
  const size_t abase = (size_t)bm * 128 * K;
  const size_t bbase = (size_t)bn * 128 * K;
  for (int k0 = 0; k0 < K; k0 += 32) {
#pragma unroll
    for (int u0 = 0; u0 < 2; u0++) {
      int u = tid + u0 * 256;
      int row = u >> 2, seg = u & 3;
      *(uint4*)(As + row * 40 + seg * 8) =
          *(const uint4*)(A + abase + (size_t)row * K + k0 + seg * 8);
      *(uint4*)(Bs + row * 40 + seg * 8) =
          *(const uint4*)(W + bbase + (size_t)row * K + k0 + seg * 8);
    }
    __syncthreads();
    s16x8 af[4], bf[4];
#pragma unroll
    for (int i = 0; i < 4; i++)
      af[i] = *(const s16x8*)(As + (wm * 64 + i * 16 + lr) * 40 + quad * 8);
#pragma unroll
    for (int j = 0; j < 4; j++)
      bf[j] = *(const s16x8*)(Bs + (wn * 64 + j * 16 + lr) * 40 + quad * 8);
#pragma unroll
    for (int i = 0; i < 4; i++)
#pragma unroll
      for (int j = 0; j < 4; j++)
        acc[i][j] = mfma16(af[i], bf[j], acc[i][j]);
    __syncthreads();
  }
#pragma unroll
  for (int i = 0; i < 4; i++)
#pragma unroll
    for (int j = 0; j < 4; j++) {
      int col = bn * 128 + wn * 64 + j * 16 + lr;
      float bv = bias ? bias[col] : 0.0f;
#pragma unroll
      for (int r = 0; r < 4; r++) {
        int row = bm * 128 + wm * 64 + i * 16 + quad * 4 + r;
        C[(size_t)row * N + col] = acc[i][j][r] + bv;
      }
    }
}

// ---------------- persistent LSTM recurrence ----------------
#define REC_BLOCKS 64
#define FLAG_STRIDE 32  // uints -> 128 B per flag, one cacheline each

// R4 theory: the invariant ~11us/step across 3 barrier designs was the
// per-step agent release (buffer_wbl2: full 4MB L2 tag walk to make h
// visible) + acquire (buffer_inv). Fix: h and flags NEVER live in L2 --
// all h/flag traffic is relaxed agent-scope atomics (sc1 -> LLC, the
// coherence point). Ordering store(h)->store(flag) via per-wave
// s_waitcnt vmcnt(0) + s_barrier; load(flag)->load(h) via branch dep +
// s_barrier. Zero cache-maintenance instructions in the loop.
//
// Wave mapping: 8 waves = 8 K-spans of 128 cols; each wave computes ALL
// 4 gates for its span (h read exactly once per block: 64KB, was 256KB).
// 8-way partial reduce in LDS.
__global__ __launch_bounds__(512) void lstm_rec(
    const float* __restrict__ ih,            // [(b*T+t)*4096 + g*1024 + d]
    const unsigned short* __restrict__ Whh,  // [4096,1024] bf16
    unsigned short* __restrict__ hbuf,       // [2][32][1024] bf16, buffer0 pre-zeroed
    unsigned short* __restrict__ ybf,        // [(b*T+t)*1024 + d] or null
    float* __restrict__ yf,                  // same, fp32, or null
    unsigned* __restrict__ flags)
{
  const int T = 256, H = 1024, B = 32;
  const int blk = blockIdx.x;
  const int tid = threadIdx.x;
  const int lane = tid & 63, wv = tid >> 6;  // wv = K-span index (0..7)
  const int lr = lane & 15, quad = lane >> 4;

  __shared__ float red[8][32][68];
  __shared__ float pre[32][68];

  // persistent weight B-fragments: gate g, kb in span ->
  // row = g*1024 + blk*16 + lr, cols wv*128 + kb*32 + quad*8
  s16x8 bfrag[4][4];
#pragma unroll
  for (int g = 0; g < 4; g++) {
    const unsigned short* wp =
        Whh + (size_t)(g * 1024 + blk * 16 + lr) * 1024 + wv * 128 + quad * 8;
#pragma unroll
    for (int kb = 0; kb < 4; kb++) bfrag[g][kb] = *(const s16x8*)(wp + kb * 32);
  }

  const int batch = tid >> 4, jj = tid & 15;  // gate/epilogue thread mapping
  float cst = 0.0f;                           // c state in register

  // reduce-phase mapping (tid -> (b2, col0) in the 32x64 pre-act tile)
  const int o = tid * 4;
  const int b2 = o >> 6, col0 = o & 63;
  const int gg_ = col0 >> 4, j0 = col0 & 15;
  const float* ihp0 = ih + (size_t)b2 * T * 4096 + gg_ * 1024 + blk * 16 + j0;
  float4 iv = *(const float4*)(ihp0);  // ih(t=0) prefetch

  unsigned phase = 1;  // no initial barrier: h(0)=0 via host memset (LLC-visible)

  for (int t = 0; t < T; t++) {
    const unsigned short* hcur = hbuf + (t & 1) * (B * H);
    unsigned* hnxt_u = (unsigned*)(hbuf + ((t + 1) & 1) * (B * H));

    // ---- MFMA: all 4 gates over this wave's 128-col K-span ----
    f32x4 acc0[4] = {}, acc1[4] = {};
    const unsigned short* hp = hcur + wv * 128 + quad * 8;
#pragma unroll
    for (int kb = 0; kb < 4; kb++) {
      s16x8 a0 = load16_llc(hp + lr * H + kb * 32);
      s16x8 a1 = load16_llc(hp + (16 + lr) * H + kb * 32);
#pragma unroll
      for (int g = 0; g < 4; g++) {
        acc0[g] = mfma16(a0, bfrag[g][kb], acc0[g]);
        acc1[g] = mfma16(a1, bfrag[g][kb], acc1[g]);
      }
    }
#pragma unroll
    for (int g = 0; g < 4; g++)
#pragma unroll
      for (int r = 0; r < 4; r++) {
        red[wv][quad * 4 + r][g * 16 + lr] = acc0[g][r];
        red[wv][16 + quad * 4 + r][g * 16 + lr] = acc1[g][r];
      }
    __syncthreads();

    // ---- reduce 8 partials + prefetched ih ----
    {
      float4 s = iv;
#pragma unroll
      for (int p = 0; p < 8; p++) {
        float4 r = *(const float4*)&red[p][b2][col0];
        s.x += r.x; s.y += r.y; s.z += r.z; s.w += r.w;
      }
      *(float4*)&pre[b2][col0] = s;
      if (t + 1 < T) iv = *(const float4*)(ihp0 + (size_t)(t + 1) * 4096);
    }
    __syncthreads();

    // ---- gates + state update; pack pairs via shfl; h -> LLC ----
    float hv; unsigned hb32;
    {
      float pi = pre[batch][jj];
      float pf = pre[batch][16 + jj];
      float pg = pre[batch][32 + jj];
      float po = pre[batch][48 + jj];
      float ig = 1.0f / (1.0f + __expf(-pi));
      float fg = 1.0f / (1.0f + __expf(-pf));
      float g  = 1.0f - 2.0f / (__expf(2.0f * pg) + 1.0f);  // tanh, safe
      float og = 1.0f / (1.0f + __expf(-po));
      cst = fg * cst + ig * g;
      hv = og * (1.0f - 2.0f / (__expf(2.0f * cst) + 1.0f));
      hb32 = f2bf(hv);
      unsigned other = __shfl_xor(hb32, 1);  // partner (same batch, jj^1)
      if ((tid & 1) == 0) {
        unsigned packed = (hb32 & 0xFFFFu) | (other << 16);
        __hip_atomic_store(hnxt_u + batch * 512 + blk * 8 + (jj >> 1), packed,
                           __ATOMIC_RELAXED, __HIP_MEMORY_SCOPE_AGENT);
      }
    }
    // each wave drains its own h-stores to the LLC, then all waves rendezvous
    asm volatile("s_waitcnt vmcnt(0)" ::: "memory");
    __syncthreads();

    // ---- signal, y-writes (off critical path), poll ----
    if (tid == 0)
      __hip_atomic_store(flags + (size_t)blk * FLAG_STRIDE, phase,
                         __ATOMIC_RELAXED, __HIP_MEMORY_SCOPE_AGENT);
    {
      size_t yi = ((size_t)(batch * T + t)) * H + blk * 16 + jj;
      if (ybf) ybf[yi] = (unsigned short)hb32;
      if (yf) yf[yi] = hv;
    }
    if (tid < 64) {
      const unsigned* f = flags + (size_t)tid * FLAG_STRIDE;
      while (__hip_atomic_load(f, __ATOMIC_RELAXED, __HIP_MEMORY_SCOPE_AGENT) < phase)
        __builtin_amdgcn_s_sleep(1);
    }
    __syncthreads();
    phase++;
  }
}

// ---------------- launcher ----------------
extern "C" void kernel_launch(void* const* d_in, const int* in_sizes, int n_in,
                              void* d_out, int out_size, void* d_ws, size_t ws_size,
                              hipStream_t stream) {
  const float* x    = (const float*)d_in[0];
  const float* Wih0 = (const float*)d_in[1];
  const float* Whh0 = (const float*)d_in[2];
  const float* b0   = (const float*)d_in[3];
  const float* Wih1 = (const float*)d_in[4];
  const float* Whh1 = (const float*)d_in[5];
  const float* b1   = (const float*)d_in[6];
  float* out = (float*)d_out;

  const size_t NW = 4096ull * 1024;  // weight elems
  const size_t NX = 8192ull * 1024;  // x / y elems (B*T x H)

  char* ws = (char*)d_ws;
  size_t off = 0;
  auto alloc = [&](size_t bytes) {
    char* p = ws + off;
    off += (bytes + 255) & ~(size_t)255;
    return p;
  };
  unsigned short* wih0b = (unsigned short*)alloc(NW * 2);
  unsigned short* whh0b = (unsigned short*)alloc(NW * 2);
  unsigned short* wih1b = (unsigned short*)alloc(NW * 2);
  unsigned short* whh1b = (unsigned short*)alloc(NW * 2);
  unsigned short* xb    = (unsigned short*)alloc(NX * 2);
  unsigned short* y1b   = (unsigned short*)alloc(NX * 2);
  float* ihbuf          = (float*)alloc(8192ull * 4096 * 4);
  unsigned short* hbuf0 = (unsigned short*)alloc(2ull * 32 * 1024 * 2);
  unsigned short* hbuf1 = (unsigned short*)alloc(2ull * 32 * 1024 * 2);
  unsigned* flags0      = (unsigned*)alloc(REC_BLOCKS * FLAG_STRIDE * 4);
  unsigned* flags1      = (unsigned*)alloc(REC_BLOCKS * FLAG_STRIDE * 4);

  // flags (both layers, contiguous) and h(0)=0 for both layers' buffer 0
  hipMemsetAsync(flags0, 0, REC_BLOCKS * FLAG_STRIDE * 4 * 2, stream);
  hipMemsetAsync(hbuf0, 0, 32 * 1024 * 2, stream);
  hipMemsetAsync(hbuf1, 0, 32 * 1024 * 2, stream);

  f2bf_kernel<<<NW / 1024, 256, 0, stream>>>(Wih0, wih0b, (int)NW);
  f2bf_kernel<<<NW / 1024, 256, 0, stream>>>(Whh0, whh0b, (int)NW);
  f2bf_kernel<<<NW / 1024, 256, 0, stream>>>(Wih1, wih1b, (int)NW);
  f2bf_kernel<<<NW / 1024, 256, 0, stream>>>(Whh1, whh1b, (int)NW);
  f2bf_kernel<<<NX / 1024, 256, 0, stream>>>(x, xb, (int)NX);

  // layer 1
  gemm_bias<<<dim3(64, 32), 256, 0, stream>>>(xb, wih0b, b0, ihbuf, 8192, 4096, 1024);
  lstm_rec<<<REC_BLOCKS, 512, 0, stream>>>(ihbuf, whh0b, hbuf0, y1b,
                                           (float*)nullptr, flags0);
  // layer 2
  gemm_bias<<<dim3(64, 32), 256, 0, stream>>>(y1b, wih1b, b1, ihbuf, 8192, 4096, 1024);
  lstm_rec<<<REC_BLOCKS, 512, 0, stream>>>(ihbuf, whh1b, hbuf1,
                                           (unsigned short*)nullptr, out, flags1);
}

// Round 5
// 2741.670 us; speedup vs baseline: 2.7365x; 1.2588x over previous
//
#include <hip/hip_runtime.h>
#include <cstdint>
#include <cstddef>

typedef short s16x8 __attribute__((ext_vector_type(8)));
typedef float f32x4 __attribute__((ext_vector_type(4)));

__device__ __forceinline__ f32x4 mfma16(s16x8 a, s16x8 b, f32x4 c) {
  return __builtin_amdgcn_mfma_f32_16x16x32_bf16(a, b, c, 0, 0, 0);
}

__device__ __forceinline__ unsigned short f2bf(float f) {
  unsigned u = __float_as_uint(f);
  u = (u + 0x7FFFu + ((u >> 16) & 1u)) >> 16;
  return (unsigned short)u;
}

// LLC-coherent 16B load as 2x8B relaxed agent atomics (sc1: bypass L2, read
// the coherence point directly -> no acquire fence / buffer_inv needed).
__device__ __forceinline__ s16x8 load16_llc(const unsigned short* p) {
  union { unsigned long long u[2]; s16x8 v; } r;
  const unsigned long long* q = (const unsigned long long*)p;
  r.u[0] = __hip_atomic_load(q,     __ATOMIC_RELAXED, __HIP_MEMORY_SCOPE_AGENT);
  r.u[1] = __hip_atomic_load(q + 1, __ATOMIC_RELAXED, __HIP_MEMORY_SCOPE_AGENT);
  return r.v;
}

// ---------------- fp32 -> bf16 conversion ----------------
__global__ void f2bf_kernel(const float* __restrict__ src,
                            unsigned short* __restrict__ dst, int n) {
  int i = (blockIdx.x * blockDim.x + threadIdx.x) * 4;
  if (i >= n) return;
  float4 v = *(const float4*)(src + i);
  ushort4 o;
  o.x = f2bf(v.x); o.y = f2bf(v.y); o.z = f2bf(v.z); o.w = f2bf(v.w);
  *(ushort4*)(dst + i) = o;
}

// ---------------- GEMM: C[M,N] = A[M,K] * W[N,K]^T + bias ----------------
__global__ __launch_bounds__(256) void gemm_bias(
    const unsigned short* __restrict__ A,
    const unsigned short* __restrict__ W,
    const float* __restrict__ bias,
    float* __restrict__ C,
    int M, int N, int K)
{
  __shared__ unsigned short As[128 * 40];
  __shared__ unsigned short Bs[128 * 40];
  const int bm = blockIdx.x, bn = blockIdx.y;
  const int tid = threadIdx.x;
  const int lane = tid & 63, wave = tid >> 6;
  const int wm = wave & 1, wn = wave >> 1;
  const int lr = lane & 15, quad = lane >> 4;
  f32x4 acc[4][4] = {};
  const size_t abase = (size_t)bm * 128 * K;
  const size_t bbase = (size_t)bn * 128 * K;
  for (int k0 = 0; k0 < K; k0 += 32) {
#pragma unroll
    for (int u0 = 0; u0 < 2; u0++) {
      int u = tid + u0 * 256;
      int row = u >> 2, seg = u & 3;
      *(uint4*)(As + row * 40 + seg * 8) =
          *(const uint4*)(A + abase + (size_t)row * K + k0 + seg * 8);
      *(uint4*)(Bs + row * 40 + seg * 8) =
          *(const uint4*)(W + bbase + (size_t)row * K + k0 + seg * 8);
    }
    __syncthreads();
    s16x8 af[4], bf[4];
#pragma unroll
    for (int i = 0; i < 4; i++)
      af[i] = *(const s16x8*)(As + (wm * 64 + i * 16 + lr) * 40 + quad * 8);
#pragma unroll
    for (int j = 0; j < 4; j++)
      bf[j] = *(const s16x8*)(Bs + (wn * 64 + j * 16 + lr) * 40 + quad * 8);
#pragma unroll
    for (int i = 0; i < 4; i++)
#pragma unroll
      for (int j = 0; j < 4; j++)
        acc[i][j] = mfma16(af[i], bf[j], acc[i][j]);
    __syncthreads();
  }
#pragma unroll
  for (int i = 0; i < 4; i++)
#pragma unroll
    for (int j = 0; j < 4; j++) {
      int col = bn * 128 + wn * 64 + j * 16 + lr;
      float bv = bias ? bias[col] : 0.0f;
#pragma unroll
      for (int r = 0; r < 4; r++) {
        int row = bm * 128 + wm * 64 + i * 16 + quad * 4 + r;
        C[(size_t)row * N + col] = acc[i][j][r] + bv;
      }
    }
}

// ---------------- fused 2-layer persistent LSTM recurrence ----------------
// R5: pipeline the layers. 128 blocks: 0-63 = layer1 (K=1024 over h1),
// 64-127 = layer2 (K=2048 over concat[h2; y1=h1], weights [Whh1|Wih1] slice
// register-resident). At super-step s: L1 computes h1(s), L2 computes
// h2(s-1). 257 super-steps replace 512 serialized steps; gemm2 + y1
// materialization deleted (L2 does its own input projection per step).
// All h exchange via R4's LLC relaxed-atomic + per-block flag pattern
// (zero cache-maintenance ops in the loop).
#define REC_BLOCKS 128
#define FLAG_STRIDE 32  // uints -> 128 B per flag, one cacheline each

__global__ __launch_bounds__(512, 2) void lstm_fused(
    const float* __restrict__ ih,            // L1: [(b*T+t)*4096 + g*1024 + d]
    const unsigned short* __restrict__ Whh0, // [4096,1024] bf16
    const unsigned short* __restrict__ Whh1, // [4096,1024] bf16
    const unsigned short* __restrict__ Wih1, // [4096,1024] bf16
    const float* __restrict__ b1,            // [4096] fp32
    unsigned short* __restrict__ h1buf,      // [2][32][1024] bf16 (buf0 zeroed)
    unsigned short* __restrict__ h2buf,      // [2][32][1024] bf16 (buf0 zeroed)
    float* __restrict__ out,                 // [32][256][1024] fp32
    unsigned* __restrict__ flags)            // 128 x 128B
{
  const int T = 256, H = 1024, B = 32;
  const int blk01 = blockIdx.x;
  const int layer = blk01 >> 6;
  const int blk = blk01 & 63;
  const int tid = threadIdx.x;
  const int lane = tid & 63, wv = tid >> 6;  // wv = K-span index (0..7)
  const int lr = lane & 15, quad = lane >> 4;

  __shared__ float red[8][32][68];
  __shared__ float pre[32][68];

  // persistent weight B-fragments.
  // L1: rows g*1024+blk*16+lr of Whh0, span wv*128 (4 kb-blocks of 32).
  // L2: rows of [Whh1 (wv<4) | Wih1 (wv>=4)], span (wv&3)*256 (8 kb-blocks).
  s16x8 bfrag[4][8];
  if (layer == 0) {
    const unsigned short* wp =
        Whh0 + (size_t)(blk * 16 + lr) * 1024 + wv * 128 + quad * 8;
#pragma unroll
    for (int g = 0; g < 4; g++)
#pragma unroll
      for (int kb = 0; kb < 4; kb++)
        bfrag[g][kb] = *(const s16x8*)(wp + (size_t)g * 1048576 + kb * 32);
  } else {
    const unsigned short* wsrc = (wv < 4) ? Whh1 : Wih1;
    const unsigned short* wp =
        wsrc + (size_t)(blk * 16 + lr) * 1024 + (wv & 3) * 256 + quad * 8;
#pragma unroll
    for (int g = 0; g < 4; g++)
#pragma unroll
      for (int kb = 0; kb < 8; kb++)
        bfrag[g][kb] = *(const s16x8*)(wp + (size_t)g * 1048576 + kb * 32);
  }

  const int batch = tid >> 4, jj = tid & 15;  // gate/epilogue thread mapping
  float cst = 0.0f;                           // c state in register

  // reduce-phase mapping (tid -> (b2, col0) in the 32x64 pre-act tile)
  const int o = tid * 4;
  const int b2 = o >> 6, col0 = o & 63;
  const int gg_ = col0 >> 4, j0 = col0 & 15;
  const float* ihp0 = ih + (size_t)b2 * T * 4096 + gg_ * 1024 + blk * 16 + j0;

  // iv: L1 = prefetched ih(t) (reloaded each step); L2 = b1 slice (constant)
  float4 iv;
  if (layer == 0) iv = *(const float4*)(ihp0);
  else            iv = *(const float4*)(b1 + gg_ * 1024 + blk * 16 + j0);

  unsigned phase = 1;  // no initial barrier: h*(0)=0 via host memset

  for (int s = 0; s <= T; s++) {
    // all reads of h1 at super-step s come from h1buf[s&1]:
    //   L1 reads h1(s-1); L2 reads y1(s-1)=h1(s-1). L1 writes h1(s)->[(s+1)&1].
    // L2's h2: reads h2(s-2) from h2buf[(s+1)&1], writes h2(s-1)->[s&1].
    const unsigned short* h1cur = h1buf + (s & 1) * (B * H);
    const bool active = (layer == 0) || (s >= 1);

    if (active) {
      f32x4 acc0[4] = {}, acc1[4] = {};
      if (layer == 0) {
        const unsigned short* hp = h1cur + wv * 128 + quad * 8;
#pragma unroll
        for (int kb = 0; kb < 4; kb++) {
          s16x8 a0 = load16_llc(hp + lr * H + kb * 32);
          s16x8 a1 = load16_llc(hp + (16 + lr) * H + kb * 32);
#pragma unroll
          for (int g = 0; g < 4; g++) {
            acc0[g] = mfma16(a0, bfrag[g][kb], acc0[g]);
            acc1[g] = mfma16(a1, bfrag[g][kb], acc1[g]);
          }
        }
      } else {
        const unsigned short* h2cur = h2buf + ((s + 1) & 1) * (B * H);
        const unsigned short* asrc = (wv < 4) ? h2cur : h1cur;
        const unsigned short* hp = asrc + (wv & 3) * 256 + quad * 8;
#pragma unroll
        for (int kb = 0; kb < 8; kb++) {
          s16x8 a0 = load16_llc(hp + lr * H + kb * 32);
          s16x8 a1 = load16_llc(hp + (16 + lr) * H + kb * 32);
#pragma unroll
          for (int g = 0; g < 4; g++) {
            acc0[g] = mfma16(a0, bfrag[g][kb], acc0[g]);
            acc1[g] = mfma16(a1, bfrag[g][kb], acc1[g]);
          }
        }
      }
#pragma unroll
      for (int g = 0; g < 4; g++)
#pragma unroll
        for (int r = 0; r < 4; r++) {
          red[wv][quad * 4 + r][g * 16 + lr] = acc0[g][r];
          red[wv][16 + quad * 4 + r][g * 16 + lr] = acc1[g][r];
        }
      __syncthreads();

      // reduce 8 partials + iv
      {
        float4 sm = iv;
#pragma unroll
        for (int p = 0; p < 8; p++) {
          float4 r = *(const float4*)&red[p][b2][col0];
          sm.x += r.x; sm.y += r.y; sm.z += r.z; sm.w += r.w;
        }
        *(float4*)&pre[b2][col0] = sm;
        if (layer == 0 && s + 1 < T)
          iv = *(const float4*)(ihp0 + (size_t)(s + 1) * 4096);
      }
      __syncthreads();

      // gates + state update; pack pairs via shfl; h -> LLC
      {
        float pi = pre[batch][jj];
        float pf = pre[batch][16 + jj];
        float pg = pre[batch][32 + jj];
        float po = pre[batch][48 + jj];
        float ig = 1.0f / (1.0f + __expf(-pi));
        float fg = 1.0f / (1.0f + __expf(-pf));
        float g  = 1.0f - 2.0f / (__expf(2.0f * pg) + 1.0f);  // tanh, safe
        float og = 1.0f / (1.0f + __expf(-po));
        cst = fg * cst + ig * g;
        float hv = og * (1.0f - 2.0f / (__expf(2.0f * cst) + 1.0f));
        unsigned hb32 = f2bf(hv);
        unsigned other = __shfl_xor(hb32, 1);  // partner (same batch, jj^1)
        unsigned* hnxt_u = (unsigned*)((layer == 0)
            ? h1buf + ((s + 1) & 1) * (B * H)
            : h2buf + (s & 1) * (B * H));
        if ((tid & 1) == 0) {
          unsigned packed = (hb32 & 0xFFFFu) | (other << 16);
          __hip_atomic_store(hnxt_u + batch * 512 + blk * 8 + (jj >> 1), packed,
                             __ATOMIC_RELAXED, __HIP_MEMORY_SCOPE_AGENT);
        }
        if (layer == 1)
          out[((size_t)(batch * T + (s - 1))) * H + blk * 16 + jj] = hv;
      }
      // drain this wave's h-stores to the LLC before the block-level signal
      asm volatile("s_waitcnt vmcnt(0)" ::: "memory");
    }
    __syncthreads();  // all waves' drains done (or inactive block rendezvous)

    if (tid == 0)
      __hip_atomic_store(flags + (size_t)blk01 * FLAG_STRIDE, phase,
                         __ATOMIC_RELAXED, __HIP_MEMORY_SCOPE_AGENT);
    if (tid < REC_BLOCKS) {
      const unsigned* f = flags + (size_t)tid * FLAG_STRIDE;
      while (__hip_atomic_load(f, __ATOMIC_RELAXED, __HIP_MEMORY_SCOPE_AGENT) < phase)
        __builtin_amdgcn_s_sleep(1);
    }
    __syncthreads();
    phase++;
  }
}

// ---------------- launcher ----------------
extern "C" void kernel_launch(void* const* d_in, const int* in_sizes, int n_in,
                              void* d_out, int out_size, void* d_ws, size_t ws_size,
                              hipStream_t stream) {
  const float* x    = (const float*)d_in[0];
  const float* Wih0 = (const float*)d_in[1];
  const float* Whh0 = (const float*)d_in[2];
  const float* b0   = (const float*)d_in[3];
  const float* Wih1 = (const float*)d_in[4];
  const float* Whh1 = (const float*)d_in[5];
  const float* b1   = (const float*)d_in[6];
  float* out = (float*)d_out;

  const size_t NW = 4096ull * 1024;  // weight elems
  const size_t NX = 8192ull * 1024;  // x elems (B*T x H)

  char* ws = (char*)d_ws;
  size_t off = 0;
  auto alloc = [&](size_t bytes) {
    char* p = ws + off;
    off += (bytes + 255) & ~(size_t)255;
    return p;
  };
  unsigned short* wih0b = (unsigned short*)alloc(NW * 2);
  unsigned short* whh0b = (unsigned short*)alloc(NW * 2);
  unsigned short* wih1b = (unsigned short*)alloc(NW * 2);
  unsigned short* whh1b = (unsigned short*)alloc(NW * 2);
  unsigned short* xb    = (unsigned short*)alloc(NX * 2);
  float* ihbuf          = (float*)alloc(8192ull * 4096 * 4);
  unsigned short* h1buf = (unsigned short*)alloc(2ull * 32 * 1024 * 2);
  unsigned short* h2buf = (unsigned short*)alloc(2ull * 32 * 1024 * 2);
  unsigned* flags       = (unsigned*)alloc(REC_BLOCKS * FLAG_STRIDE * 4);

  hipMemsetAsync(flags, 0, REC_BLOCKS * FLAG_STRIDE * 4, stream);
  hipMemsetAsync(h1buf, 0, 2ull * 32 * 1024 * 2, stream);
  hipMemsetAsync(h2buf, 0, 2ull * 32 * 1024 * 2, stream);

  f2bf_kernel<<<NW / 1024, 256, 0, stream>>>(Wih0, wih0b, (int)NW);
  f2bf_kernel<<<NW / 1024, 256, 0, stream>>>(Whh0, whh0b, (int)NW);
  f2bf_kernel<<<NW / 1024, 256, 0, stream>>>(Wih1, wih1b, (int)NW);
  f2bf_kernel<<<NW / 1024, 256, 0, stream>>>(Whh1, whh1b, (int)NW);
  f2bf_kernel<<<NX / 1024, 256, 0, stream>>>(x, xb, (int)NX);

  // layer-1 input projection (one big GEMM)
  gemm_bias<<<dim3(64, 32), 256, 0, stream>>>(xb, wih0b, b0, ihbuf, 8192, 4096, 1024);
  // fused 2-layer pipelined recurrence (257 super-steps)
  lstm_fused<<<REC_BLOCKS, 512, 0, stream>>>(ihbuf, whh0b, whh1b, wih1b, b1,
                                             h1buf, h2buf, out, flags);
}

// Round 6
// 1319.009 us; speedup vs baseline: 5.6880x; 2.0786x over previous
//
#include <hip/hip_runtime.h>
#include <cstdint>
#include <cstddef>

typedef short s16x8 __attribute__((ext_vector_type(8)));
typedef float f32x4 __attribute__((ext_vector_type(4)));

__device__ __forceinline__ f32x4 mfma16(s16x8 a, s16x8 b, f32x4 c) {
  return __builtin_amdgcn_mfma_f32_16x16x32_bf16(a, b, c, 0, 0, 0);
}

__device__ __forceinline__ unsigned short f2bf(float f) {
  unsigned u = __float_as_uint(f);
  u = (u + 0x7FFFu + ((u >> 16) & 1u)) >> 16;
  return (unsigned short)u;
}

// LLC-coherent 16B ops as 2x8B relaxed agent atomics (bypass L1/L2, hit the
// coherence point directly -> no fences / cache maintenance anywhere).
__device__ __forceinline__ s16x8 load16_llc(const unsigned short* p) {
  union { unsigned long long u[2]; s16x8 v; } r;
  const unsigned long long* q = (const unsigned long long*)p;
  r.u[0] = __hip_atomic_load(q,     __ATOMIC_RELAXED, __HIP_MEMORY_SCOPE_AGENT);
  r.u[1] = __hip_atomic_load(q + 1, __ATOMIC_RELAXED, __HIP_MEMORY_SCOPE_AGENT);
  return r.v;
}
__device__ __forceinline__ float4 load16f_llc(const float* p) {
  union { unsigned long long u[2]; float4 v; } r;
  const unsigned long long* q = (const unsigned long long*)p;
  r.u[0] = __hip_atomic_load(q,     __ATOMIC_RELAXED, __HIP_MEMORY_SCOPE_AGENT);
  r.u[1] = __hip_atomic_load(q + 1, __ATOMIC_RELAXED, __HIP_MEMORY_SCOPE_AGENT);
  return r.v;
}
__device__ __forceinline__ void store16f_llc(float* p, float4 v) {
  union { float4 v; unsigned long long u[2]; } r; r.v = v;
  unsigned long long* q = (unsigned long long*)p;
  __hip_atomic_store(q,     r.u[0], __ATOMIC_RELAXED, __HIP_MEMORY_SCOPE_AGENT);
  __hip_atomic_store(q + 1, r.u[1], __ATOMIC_RELAXED, __HIP_MEMORY_SCOPE_AGENT);
}
__device__ __forceinline__ void spin_tag(const int* t, int target) {
  while (__hip_atomic_load(t, __ATOMIC_RELAXED, __HIP_MEMORY_SCOPE_AGENT) < target)
    __builtin_amdgcn_s_sleep(1);
}

// ---------------- fp32 -> bf16 conversion ----------------
__global__ void f2bf_kernel(const float* __restrict__ src,
                            unsigned short* __restrict__ dst, int n) {
  int i = (blockIdx.x * blockDim.x + threadIdx.x) * 4;
  if (i >= n) return;
  float4 v = *(const float4*)(src + i);
  ushort4 o;
  o.x = f2bf(v.x); o.y = f2bf(v.y); o.z = f2bf(v.z); o.w = f2bf(v.w);
  *(ushort4*)(dst + i) = o;
}

// ---------------- GEMM: C[M,N] = A[M,K] * W[N,K]^T + bias ----------------
__global__ __launch_bounds__(256) void gemm_bias(
    const unsigned short* __restrict__ A,
    const unsigned short* __restrict__ W,
    const float* __restrict__ bias,
    float* __restrict__ C,
    int M, int N, int K)
{
  __shared__ unsigned short As[128 * 40];
  __shared__ unsigned short Bs[128 * 40];
  const int bm = blockIdx.x, bn = blockIdx.y;
  const int tid = threadIdx.x;
  const int lane = tid & 63, wave = tid >> 6;
  const int wm = wave & 1, wn = wave >> 1;
  const int lr = lane & 15, quad = lane >> 4;
  f32x4 acc[4][4] = {};
  const size_t abase = (size_t)bm * 128 * K;
  const size_t bbase = (size_t)bn * 128 * K;
  for (int k0 = 0; k0 < K; k0 += 32) {
#pragma unroll
    for (int u0 = 0; u0 < 2; u0++) {
      int u = tid + u0 * 256;
      int row = u >> 2, seg = u & 3;
      *(uint4*)(As + row * 40 + seg * 8) =
          *(const uint4*)(A + abase + (size_t)row * K + k0 + seg * 8);
      *(uint4*)(Bs + row * 40 + seg * 8) =
          *(const uint4*)(W + bbase + (size_t)row * K + k0 + seg * 8);
    }
    __syncthreads();
    s16x8 af[4], bf[4];
#pragma unroll
    for (int i = 0; i < 4; i++)
      af[i] = *(const s16x8*)(As + (wm * 64 + i * 16 + lr) * 40 + quad * 8);
#pragma unroll
    for (int j = 0; j < 4; j++)
      bf[j] = *(const s16x8*)(Bs + (wn * 64 + j * 16 + lr) * 40 + quad * 8);
#pragma unroll
    for (int i = 0; i < 4; i++)
#pragma unroll
      for (int j = 0; j < 4; j++)
        acc[i][j] = mfma16(af[i], bf[j], acc[i][j]);
    __syncthreads();
  }
#pragma unroll
  for (int i = 0; i < 4; i++)
#pragma unroll
    for (int j = 0; j < 4; j++) {
      int col = bn * 128 + wn * 64 + j * 16 + lr;
      float bv = bias ? bias[col] : 0.0f;
#pragma unroll
      for (int r = 0; r < 4; r++) {
        int row = bm * 128 + wm * 64 + i * 16 + quad * 4 + r;
        C[(size_t)row * N + col] = acc[i][j][r] + bv;
      }
    }
}

// ---------------- dataflow 3-stage pipelined LSTM ----------------
// R6: NO grid barrier. 192 blocks in 3 classes of 64; each block owns 16
// output dims with a register-resident 64-row x 1024-col weight slice
// (bfrag[4][4] = 64 VGPR, guaranteed resident; R5's K=2048 slice wasn't).
//   cls0 L1 : h1(s) = gate(ih(s) + Whh0 h1(s-1))   tags1
//   cls1 L2b: P(s)  = Wih1 h1(s) + b1  -> 4-ring   tags2b (point-to-point)
//   cls2 L2a: h2(s) = gate(P(s) + Whh1 h2(s-1))    tags2a; writes out
// Tag = #iters completed (int, relaxed agent). Each block proceeds when ITS
// producers' tags arrive (one-way publish), no rendezvous. Anti-trample:
// L1 guards on all tags2b >= s-1 (h1 slot reuse); L2b on partner tag2a >=
// s-3 (P ring reuse). Deadlock-free: steady lags L1 >= L2b >= L2a.
#define TSTRIDE 32          // ints per tag (128B line)
#define HSLOT  32768        // shorts per h slot: 64 blk * 32 batch * 16 dim
#define PSLOT  (64 * 2048)  // floats per P slot: 64 blk * 32 batch * 64 col

__global__ __launch_bounds__(512, 2) void lstm_pipe(
    const float* __restrict__ ih,             // [(b*T+t)*4096 + g*1024 + d]
    const unsigned short* __restrict__ Whh0,  // [4096,1024] bf16
    const unsigned short* __restrict__ Wih1,  // [4096,1024] bf16
    const unsigned short* __restrict__ Whh1,  // [4096,1024] bf16
    const float* __restrict__ b1,             // [4096] fp32
    unsigned short* __restrict__ h1x,         // [2][64][32][16] bf16 (zeroed)
    unsigned short* __restrict__ h2x,         // [2][64][32][16] bf16 (zeroed)
    float* __restrict__ Pring,                // [4][64][32][64] fp32
    int* __restrict__ tags,                   // [3][64][TSTRIDE] (zeroed)
    float* __restrict__ out)                  // [32][256][1024] fp32
{
  const int T = 256, H = 1024;
  const int cls = blockIdx.x >> 6;
  const int blk = blockIdx.x & 63;
  const int tid = threadIdx.x;
  const int lane = tid & 63, wv = tid >> 6;
  const int lr = lane & 15, quad = lane >> 4;

  __shared__ float red[8][32][68];
  __shared__ float pre[32][68];

  const unsigned short* W = (cls == 0) ? Whh0 : (cls == 1) ? Wih1 : Whh1;
  s16x8 bfrag[4][4];
#pragma unroll
  for (int g = 0; g < 4; g++) {
    const unsigned short* wp =
        W + (size_t)(g * 1024 + blk * 16 + lr) * 1024 + wv * 128 + quad * 8;
#pragma unroll
    for (int kb = 0; kb < 4; kb++) bfrag[g][kb] = *(const s16x8*)(wp + kb * 32);
  }

  int* tagL1  = tags;
  int* tagL2b = tags + 64 * TSTRIDE;
  int* tagL2a = tags + 128 * TSTRIDE;
  int* mytag  = tags + (cls * 64 + blk) * TSTRIDE;

  const int batch = tid >> 4, jj = tid & 15;
  float cst = 0.0f;

  const int o = tid * 4;
  const int b2 = o >> 6, col0 = o & 63;
  const int gg_ = col0 >> 4, j0 = col0 & 15;
  const float* ihp0 = ih + (size_t)b2 * T * 4096 + gg_ * 1024 + blk * 16 + j0;

  float4 iv = {0.f, 0.f, 0.f, 0.f};
  if (cls == 0)      iv = *(const float4*)(ihp0);
  else if (cls == 1) iv = *(const float4*)(b1 + gg_ * 1024 + blk * 16 + j0);

  for (int s = 0; s < T; s++) {
    // ---- poll ONLY my producers (one-way, no rendezvous) ----
    if (cls == 0) {
      if (lane < 8) spin_tag(tagL1 + (8 * wv + lane) * TSTRIDE, s);
    } else if (cls == 1) {
      if (lane < 8) spin_tag(tagL1 + (8 * wv + lane) * TSTRIDE, s + 1);
      if (lane == 0) spin_tag(tagL2a + blk * TSTRIDE, s - 3);  // P-ring guard
    } else {
      if (lane < 8) spin_tag(tagL2a + (8 * wv + lane) * TSTRIDE, s);
      if (lane == 0) spin_tag(tagL2b + blk * TSTRIDE, s + 1);  // partner P(s)
    }
    asm volatile("" ::: "memory");  // no hoisting data loads above polls

    // source: cls0 h1(s-1); cls1 h1(s); cls2 h2(s-1). slot = step & 1.
    const unsigned short* src =
        (cls == 0) ? h1x + ((s + 1) & 1) * HSLOT
      : (cls == 1) ? h1x + (s & 1) * HSLOT
                   : h2x + ((s + 1) & 1) * HSLOT;

    f32x4 acc0[4] = {}, acc1[4] = {};
#pragma unroll
    for (int kb = 0; kb < 4; kb++) {
      const int d = wv * 128 + kb * 32 + quad * 8;       // global k-dim
      const unsigned short* pp = src + (d >> 4) * 512 + (d & 15);
      s16x8 a0 = load16_llc(pp + lr * 16);
      s16x8 a1 = load16_llc(pp + (16 + lr) * 16);
#pragma unroll
      for (int g = 0; g < 4; g++) {
        acc0[g] = mfma16(a0, bfrag[g][kb], acc0[g]);
        acc1[g] = mfma16(a1, bfrag[g][kb], acc1[g]);
      }
    }
#pragma unroll
    for (int g = 0; g < 4; g++)
#pragma unroll
      for (int r = 0; r < 4; r++) {
        red[wv][quad * 4 + r][g * 16 + lr] = acc0[g][r];
        red[wv][16 + quad * 4 + r][g * 16 + lr] = acc1[g][r];
      }
    __syncthreads();  // A

    // ---- reduce 8 partials + iv (cls2: iv = partner's P(s) from ring) ----
    float4 sm;
    if (cls == 2)
      sm = load16f_llc(Pring + (size_t)(s & 3) * PSLOT + blk * 2048 + b2 * 64 + col0);
    else
      sm = iv;
#pragma unroll
    for (int p = 0; p < 8; p++) {
      float4 r = *(const float4*)&red[p][b2][col0];
      sm.x += r.x; sm.y += r.y; sm.z += r.z; sm.w += r.w;
    }

    if (cls == 0) {
      if (tid < 64) spin_tag(tagL2b + tid * TSTRIDE, s - 1);  // h1-slot guard
      if (s + 1 < T) iv = *(const float4*)(ihp0 + (size_t)(s + 1) * 4096);
    }

    if (cls == 1) {
      // P(s) = pre-activations, straight to the ring (no gates, no syncB)
      store16f_llc(Pring + (size_t)(s & 3) * PSLOT + blk * 2048 + b2 * 64 + col0, sm);
    } else {
      *(float4*)&pre[b2][col0] = sm;
      __syncthreads();  // B
      float pi = pre[batch][jj];
      float pf = pre[batch][16 + jj];
      float pg = pre[batch][32 + jj];
      float po = pre[batch][48 + jj];
      float ig = 1.0f / (1.0f + __expf(-pi));
      float fg = 1.0f / (1.0f + __expf(-pf));
      float g  = 1.0f - 2.0f / (__expf(2.0f * pg) + 1.0f);  // tanh, safe
      float og = 1.0f / (1.0f + __expf(-po));
      cst = fg * cst + ig * g;
      float hv = og * (1.0f - 2.0f / (__expf(2.0f * cst) + 1.0f));
      unsigned hb32 = f2bf(hv);
      unsigned other = __shfl_xor(hb32, 1);  // partner (same batch, jj^1)
      unsigned* dst = (unsigned*)((cls == 0 ? h1x : h2x) + (s & 1) * HSLOT);
      if ((tid & 1) == 0)
        __hip_atomic_store(dst + blk * 256 + batch * 8 + (jj >> 1),
                           (hb32 & 0xFFFFu) | (other << 16),
                           __ATOMIC_RELAXED, __HIP_MEMORY_SCOPE_AGENT);
      if (cls == 2)
        out[((size_t)(batch * T + s)) * H + blk * 16 + jj] = hv;
    }
    // drain this wave's stores to the LLC, rendezvous block, publish tag
    asm volatile("s_waitcnt vmcnt(0)" ::: "memory");
    __syncthreads();  // C
    if (tid == 0)
      __hip_atomic_store(mytag, s + 1, __ATOMIC_RELAXED, __HIP_MEMORY_SCOPE_AGENT);
  }
}

// ---------------- launcher ----------------
extern "C" void kernel_launch(void* const* d_in, const int* in_sizes, int n_in,
                              void* d_out, int out_size, void* d_ws, size_t ws_size,
                              hipStream_t stream) {
  const float* x    = (const float*)d_in[0];
  const float* Wih0 = (const float*)d_in[1];
  const float* Whh0 = (const float*)d_in[2];
  const float* b0   = (const float*)d_in[3];
  const float* Wih1 = (const float*)d_in[4];
  const float* Whh1 = (const float*)d_in[5];
  const float* b1   = (const float*)d_in[6];
  float* out = (float*)d_out;

  const size_t NW = 4096ull * 1024;  // weight elems
  const size_t NX = 8192ull * 1024;  // x elems (B*T x H)

  char* ws = (char*)d_ws;
  size_t off = 0;
  auto alloc = [&](size_t bytes) {
    char* p = ws + off;
    off += (bytes + 255) & ~(size_t)255;
    return p;
  };
  unsigned short* wih0b = (unsigned short*)alloc(NW * 2);
  unsigned short* whh0b = (unsigned short*)alloc(NW * 2);
  unsigned short* wih1b = (unsigned short*)alloc(NW * 2);
  unsigned short* whh1b = (unsigned short*)alloc(NW * 2);
  unsigned short* xb    = (unsigned short*)alloc(NX * 2);
  float* ihbuf          = (float*)alloc(8192ull * 4096 * 4);
  unsigned short* h1x   = (unsigned short*)alloc(2ull * HSLOT * 2);
  unsigned short* h2x   = (unsigned short*)alloc(2ull * HSLOT * 2);
  float* Pring          = (float*)alloc(4ull * PSLOT * 4);
  int* tags             = (int*)alloc(3ull * 64 * TSTRIDE * 4);

  hipMemsetAsync(tags, 0, 3ull * 64 * TSTRIDE * 4, stream);
  hipMemsetAsync(h1x, 0, 2ull * HSLOT * 2, stream);
  hipMemsetAsync(h2x, 0, 2ull * HSLOT * 2, stream);

  f2bf_kernel<<<NW / 1024, 256, 0, stream>>>(Wih0, wih0b, (int)NW);
  f2bf_kernel<<<NW / 1024, 256, 0, stream>>>(Whh0, whh0b, (int)NW);
  f2bf_kernel<<<NW / 1024, 256, 0, stream>>>(Wih1, wih1b, (int)NW);
  f2bf_kernel<<<NW / 1024, 256, 0, stream>>>(Whh1, whh1b, (int)NW);
  f2bf_kernel<<<NX / 1024, 256, 0, stream>>>(x, xb, (int)NX);

  // layer-1 input projection (one big GEMM), then the dataflow pipeline
  gemm_bias<<<dim3(64, 32), 256, 0, stream>>>(xb, wih0b, b0, ihbuf, 8192, 4096, 1024);
  lstm_pipe<<<192, 512, 0, stream>>>(ihbuf, whh0b, wih1b, whh1b, b1,
                                     h1x, h2x, Pring, tags, out);
}